// Round 8
// baseline (132.681 us; speedup 1.0000x reference)
//
#include <hip/hip_runtime.h>

// B=8, T=2048, C=768, HS=64. fp32 in/out; bf16 MFMA internally.
// R16 = R15 with the q/k epilogue stores made WIDE. R15's residual ~40us of
// fused-dispatch stall: ~2M scalar 2-byte sc0sc1 stores (q/k epilogue) that
// can't write-combine (write-through semantics) and serialize at the MALL
// before each block's vmcnt-drain + barrier arrive. Fix: stage the 32x128
// q/k tile through the (dead) proj LDS, emit 1024 coalesced 16B st16_sys per
// block (2/thread) -- 12x fewer transactions, 8x wider. wtf/vfb stores were
// already 16B. Everything else R15-verbatim.

typedef short bf16x8 __attribute__((ext_vector_type(8)));  // 8 bf16 = 4 VGPR
typedef short bf16x4 __attribute__((ext_vector_type(4)));  // 4 bf16 = 2 VGPR
typedef float f32x4  __attribute__((ext_vector_type(4)));
typedef unsigned u32x2 __attribute__((ext_vector_type(2)));
typedef unsigned u32x4 __attribute__((ext_vector_type(4)));

#define MFMA_BF16(a, b, c) __builtin_amdgcn_mfma_f32_16x16x32_bf16((a), (b), (c), 0, 0, 0)

#if __has_builtin(__builtin_amdgcn_mfma_f32_16x16x16bf16_1k)
#define HAVE_MFMA16 1
#define MFMA16(a, b, c) __builtin_amdgcn_mfma_f32_16x16x16bf16_1k((a), (b), (c), 0, 0, 0)
#else
#define HAVE_MFMA16 0
#endif

// scale = C^-0.5 * log2(e), folded into Wq at prep time
#define SCALE_LOG2E 0.05206626f

__device__ __forceinline__ unsigned rbf(float f) {  // RNE bf16 in high 16 bits
  unsigned u = __builtin_bit_cast(unsigned, f);
  return u + 0x7fffu + ((u >> 16) & 1u);
}
__device__ __forceinline__ short f2bf(float f) { return (short)(rbf(f) >> 16); }
__device__ __forceinline__ unsigned pkbf(float a, float b) {  // [lo=a, hi=b]
  return (rbf(a) >> 16) | (rbf(b) & 0xFFFF0000u);
}
__device__ __forceinline__ float bsum(unsigned dw) {  // sum of 2 packed bf16
  float lo = __builtin_bit_cast(float, dw << 16);
  float hi = __builtin_bit_cast(float, dw & 0xFFFF0000u);
  return lo + hi;
}

__device__ __forceinline__ void load_lds16(const void* g, void* l) {
  __builtin_amdgcn_global_load_lds(
      (const __attribute__((address_space(1))) void*)g,
      (__attribute__((address_space(3))) void*)l, 16, 0, 0);
}

// System-scope write-through store (gfx950 spellings: sc0 sc1; glc/slc do
// not assemble). Data reaches the MALL coherence point; no dirty L2 lines.
__device__ __forceinline__ void st16_sys(void* p, u32x4 v) {
  asm volatile("global_store_dwordx4 %0, %1, off sc0 sc1" ::"v"(p), "v"(v)
               : "memory");
}

// Fence-free grid barrier. Prereq: all cross-phase data stored write-through
// (above). Drain own stores (asm stores are invisible to compiler waitcnt) ->
// block barrier -> striped device-scope arrive -> load-only poll -> compiler
// barrier. Timeout failsafe degrades to a visible wrong answer, never a hang.
__device__ __forceinline__ void gbar(unsigned* ctr, unsigned target) {
  asm volatile("s_waitcnt vmcnt(0)" ::: "memory");
  __syncthreads();
  if (threadIdx.x == 0) {
    atomicAdd(&ctr[(blockIdx.x & 7) * 32], 1u);
    long long t0 = (long long)__builtin_amdgcn_s_memtime();
    for (;;) {
      unsigned s = 0;
#pragma unroll
      for (int i = 0; i < 8; ++i)
        s += __hip_atomic_load(&ctr[i * 32], __ATOMIC_RELAXED,
                               __HIP_MEMORY_SCOPE_AGENT);
      if (s >= target) break;
      __builtin_amdgcn_s_sleep(2);
      if ((long long)__builtin_amdgcn_s_memtime() - t0 > (1LL << 28)) break;
    }
    asm volatile("" ::: "memory");  // keep later loads below the poll
  }
  __syncthreads();
}

// ---------------------------------------------------------------------------
// Fused kernel. 512 blocks x 256 threads, plain launch.
// LDS union (29696 B = 14848 shorts):
//   proj: xa[2][32][40] = shorts [0,2560) | wb[2][6144] = shorts [2560,14848)
//   proj epilogue: qk[32][128] = shorts [0,4096)  (xa/wb dead)
//   attn: ksw 4 waves x 2304 shorts = [0,9216) ; combine overlay 6912 floats
// Co-residency: __launch_bounds__(256,2) + 29.7 KB LDS -> 2 blocks/CU x 256
// CU = 512 = grid, compile-enforced.
// ---------------------------------------------------------------------------
__global__ __launch_bounds__(256, 2) void fused_kernel(
    const float* __restrict__ x, const float* __restrict__ Wk,
    const float* __restrict__ Wq, const float* __restrict__ Wv,
    short* __restrict__ wtf, short* __restrict__ qb, short* __restrict__ kb,
    short* __restrict__ vfb, unsigned* __restrict__ bar,
    float* __restrict__ out) {
  __shared__ __attribute__((aligned(16))) short lds[14848];

  const int tid  = threadIdx.x;
  const int wave = tid >> 6;
  const int lane = tid & 63;
  const int quad = lane >> 4;
  const int col  = lane & 15;

  // ============== phase A: prep wtf (B-fragment-order weights) =============
  // wtf[ks 0..23][nt 0..11][lane 0..63][8 bf16]; nt 0-3 Wq (pre-scaled),
  // 4-7 Wk, 8-11 Wv.
  {
    int gid = blockIdx.x * 256 + tid;
    if (gid < 24 * 12 * 64) {
      int ks   = gid / 768;
      int rem  = gid - ks * 768;
      int nt   = rem >> 6;
      int pl   = rem & 63;
      int pq = pl >> 4, pc = pl & 15;
      const float* W = (nt < 4) ? Wq : (nt < 8) ? Wk : Wv;
      float s = (nt < 4) ? SCALE_LOG2E : 1.0f;
      int h  = (nt & 3) * 16 + pc;
      int k0 = ks * 32 + pq * 8;
      bf16x8 v;
#pragma unroll
      for (int j = 0; j < 8; ++j) v[j] = f2bf(W[(k0 + j) * 64 + h] * s);
      st16_sys(wtf + (size_t)gid * 8, __builtin_bit_cast(u32x4, v));
    }
  }
  gbar(bar, 512);

  // ============== phase B: projections (R6 structure) ======================
  {
    short (*xa)[32][40] = (short(*)[32][40]) & lds[0];      // 2x32x40
    short (*wb)[6144]   = (short(*)[6144]) & lds[2560];     // 2x6144

    const int msub = wave >> 1;
    const int nh   = wave & 1;
    const int m0   = blockIdx.x * 32;

    const int srow = tid >> 3, sc4 = tid & 7;
    const float* xsrc = x + (size_t)(m0 + srow) * 768 + sc4 * 4;

    auto dma_wt = [&](int ks, int buf) {
      const short* wsrc = wtf + (size_t)ks * 6144;
#pragma unroll
      for (int i = 0; i < 3; ++i) {
        int seg = wave * 3 + i;
        load_lds16(wsrc + seg * 512 + lane * 8, &wb[buf][seg * 512]);
      }
    };
    auto write_xa = [&](int buf, const float4& xv) {
      unsigned lo = pkbf(xv.x, xv.y);
      unsigned hi = pkbf(xv.z, xv.w);
      *(uint2*)&xa[buf][srow][sc4 * 4] = make_uint2(lo, hi);
    };

    f32x4 acc[6];
#pragma unroll
    for (int i = 0; i < 6; ++i) acc[i] = (f32x4){0.f, 0.f, 0.f, 0.f};

    float4 xv = *(const float4*)xsrc;
    dma_wt(0, 0);
    write_xa(0, xv);
    xv = *(const float4*)(xsrc + 32);

    for (int ks = 0; ks < 24; ++ks) {
      const int cur = ks & 1;
      __syncthreads();  // drains DMA(ks) [vmcnt] + xa writes [lgkm]

      if (ks + 1 < 24) {
        dma_wt(ks + 1, cur ^ 1);
        write_xa(cur ^ 1, xv);
        if (ks + 2 < 24) xv = *(const float4*)(xsrc + (ks + 2) * 32);
      }

      bf16x8 af = *(const bf16x8*)&xa[cur][msub * 16 + col][quad * 8];
#pragma unroll
      for (int i = 0; i < 6; ++i) {
        bf16x8 bfr = *(const bf16x8*)&wb[cur][((nh * 6 + i) * 64 + lane) * 8];
        acc[i] = MFMA_BF16(af, bfr, acc[i]);
      }
    }

    // ---- epilogue (R16). acc C/D layout: col = lane&15, row = quad*4+rr.
    // Stage q/k through LDS tile qk[32 tok][128] (cols 0-63 q-h, 64-127 k-h),
    // then 2 coalesced 16B write-through stores per thread. V unchanged
    // (already wide st16_sys in MFMA16 A-frag order).
    const int b = m0 >> 11;
    const int v = (m0 & 2047) >> 5;  // 32-key visit within batch

    __syncthreads();     // all waves past their last xa/wb reads
    short* qk = lds;     // overlays xa/wb
#pragma unroll
    for (int i = 0; i < 6; ++i) {
      int nt = nh * 6 + i;
      if (nt < 8) {  // q: nt 0-3 -> cols (nt&3)*16+col; k: nt 4-7 -> +64
        int cb = ((nt < 4) ? 0 : 64) + (nt & 3) * 16 + col;
        int r0 = msub * 16 + quad * 4;
#pragma unroll
        for (int r = 0; r < 4; ++r) qk[(r0 + r) * 128 + cb] = f2bf(acc[i][r]);
      }
    }
    if (nh == 1) {
      // V (acc[2..5]): pack straight into MFMA16 A-frag order.
#pragma unroll
      for (int pg = 0; pg < 2; ++pg) {
        unsigned w0 = pkbf(acc[2 + 2 * pg][0], acc[2 + 2 * pg][1]);
        unsigned w1 = pkbf(acc[2 + 2 * pg][2], acc[2 + 2 * pg][3]);
        unsigned w2 = pkbf(acc[3 + 2 * pg][0], acc[3 + 2 * pg][1]);
        unsigned w3 = pkbf(acc[3 + 2 * pg][2], acc[3 + 2 * pg][3]);
        u32x4 pu = {w0, w1, w2, w3};
        st16_sys(vfb + ((size_t)((b * 64 + v) * 4 + msub * 2 + pg)) * 512 + lane * 8,
                 pu);
      }
    }
    __syncthreads();
    {
      const int row = tid >> 3, sub = tid & 7;  // 32 rows x 8 col-groups
      short* dst = ((sub < 4) ? qb : kb) + (size_t)(m0 + row) * 64 + (sub & 3) * 16;
      const short* src = &qk[row * 128 + sub * 16];
      st16_sys(dst, *(const u32x4*)(src));
      st16_sys(dst + 8, *(const u32x4*)(src + 8));
    }
  }
  gbar(bar + 8 * 32, 512);

  // ============== phase C: flash attention (R8 4-way split) ================
  {
    short* ksw = &lds[wave * 2304];  // wave-private K tile [32 key][72]

    const int bx = blockIdx.x;
    const int b  = bx & 7;
    // Persistent placement pairs bx with bx+256 on one CU (round-robin
    // dispatch). Map qt so each pair is (qt, 63-qt): constant work per CU.
    const int qt = (bx < 256) ? (63 - (bx >> 3)) : ((bx - 256) >> 3);
    const size_t qbase = (size_t)b * 2048 + qt * 32;

    // Q B-frags (pre-scaled): qf[qs][c] -> Q[q=col][h=c*32+quad*8+j]
    bf16x8 qf[2][2];
#pragma unroll
    for (int qs = 0; qs < 2; ++qs)
#pragma unroll
      for (int c = 0; c < 2; ++c)
        qf[qs][c] = *(const bf16x8*)(qb + (qbase + qs * 16 + col) * 64 + c * 32 + quad * 8);

    f32x4 o[2][4];  // O^T accumulators: [qs][ht], row=h_local, col=q
#pragma unroll
    for (int qs = 0; qs < 2; ++qs)
#pragma unroll
      for (int ht = 0; ht < 4; ++ht) o[qs][ht] = (f32x4){0.f, 0.f, 0.f, 0.f};
    float osum[2] = {0.f, 0.f};

    const int nv = qt + 1;  // 32-key visits; wave w takes w, w+4, ...
    const int mycount = (nv > wave) ? ((nv - wave + 3) >> 2) : 0;

    const short* kB = kb + (size_t)b * 2048 * 64;
    const short* vB = vfb + (size_t)b * 64 * 4 * 512;

    bf16x8 kreg[4], vv[4];
    auto issue_k = [&](int v) {  // contiguous 4 KB
      const short* ksrc = kB + (size_t)v * 32 * 64;
#pragma unroll
      for (int it = 0; it < 4; ++it)
        kreg[it] = *(const bf16x8*)(ksrc + lane * 8 + it * 512);
    };
    auto issue_v = [&](int v) {  // frag-order, 1 KB contiguous per load
      const short* vp = vB + (size_t)v * 4 * 512;
#pragma unroll
      for (int g = 0; g < 4; ++g)
        vv[g] = *(const bf16x8*)(vp + g * 512 + lane * 8);
    };
    if (mycount > 0) issue_k(wave);

    for (int i = 0; i < mycount; ++i) {
      const int v = wave + i * 4;

      issue_v(v);  // flies through commit + S^T + softmax (~300 cyc)

      // ---- commit prefetched K to private LDS (consumes kreg) ----
#pragma unroll
      for (int it = 0; it < 4; ++it) {
        int e = lane * 8 + it * 512;
        *(bf16x8*)&ksw[(e >> 6) * 72 + (e & 63)] = kreg[it];  // [key][h]
      }
      if (i + 1 < mycount) issue_k(v + 4);  // K prefetch for next visit

      // ---- S^T = K Q^T : A=K[key][h] from LDS, B=Q (regs) ----
      f32x4 st[2][2];  // [qs][t: 16-key tile]
#pragma unroll
      for (int qs = 0; qs < 2; ++qs)
#pragma unroll
        for (int t = 0; t < 2; ++t) st[qs][t] = (f32x4){0.f, 0.f, 0.f, 0.f};
#pragma unroll
      for (int t = 0; t < 2; ++t) {
        const bf16x8 a0 = *(const bf16x8*)&ksw[(t * 16 + col) * 72 + quad * 8];
        const bf16x8 a1 = *(const bf16x8*)&ksw[(t * 16 + col) * 72 + 32 + quad * 8];
#pragma unroll
        for (int qs = 0; qs < 2; ++qs) {
          st[qs][t] = MFMA_BF16(a0, qf[qs][0], st[qs][t]);
          st[qs][t] = MFMA_BF16(a1, qf[qs][1], st[qs][t]);
        }
      }

      // ---- p = exp2(s); causal mask on diagonal visit ----
      const bool diag = (v == qt);  // wave-uniform
      unsigned d[2][2][2];          // packed bf16 P: [qs][t][pair]
#pragma unroll
      for (int qs = 0; qs < 2; ++qs) {
        float part = 0.f;
#pragma unroll
        for (int t = 0; t < 2; ++t) {
          float pr[4];
#pragma unroll
          for (int rr = 0; rr < 4; ++rr) {
            float sv = st[qs][t][rr];
            if (diag && (t * 16 + quad * 4 + rr) > (qs * 16 + col)) sv = -1e30f;
            pr[rr] = __builtin_amdgcn_exp2f(sv);
          }
          d[qs][t][0] = pkbf(pr[0], pr[1]);
          d[qs][t][1] = pkbf(pr[2], pr[3]);
          part += bsum(d[qs][t][0]) + bsum(d[qs][t][1]);
        }
        part += __shfl_xor(part, 16);
        part += __shfl_xor(part, 32);
        osum[qs] += part;
      }

#if HAVE_MFMA16
      // ---- O^T += V^T P^T : V frags straight from vv regs, P from d regs --
#pragma unroll
      for (int t = 0; t < 2; ++t)
#pragma unroll
        for (int pg = 0; pg < 2; ++pg) {
          uint4 u = __builtin_bit_cast(uint4, vv[t * 2 + pg]);
          u32x2 l2 = {u.x, u.y}, h2 = {u.z, u.w};
          bf16x4 vlo = __builtin_bit_cast(bf16x4, l2);  // ht = 2*pg
          bf16x4 vhi = __builtin_bit_cast(bf16x4, h2);  // ht = 2*pg+1
#pragma unroll
          for (int qs = 0; qs < 2; ++qs) {
            u32x2 pd = {d[qs][t][0], d[qs][t][1]};
            bf16x4 pb = __builtin_bit_cast(bf16x4, pd);
            o[qs][2 * pg]     = MFMA16(vlo, pb, o[qs][2 * pg]);
            o[qs][2 * pg + 1] = MFMA16(vhi, pb, o[qs][2 * pg + 1]);
          }
        }
#else
      // ---- fallback: shfl-transpose P (K=32) + shfl-gather V bf16x8 ----
      bf16x8 pbf[2];
#pragma unroll
      for (int qs = 0; qs < 2; ++qs) {
        unsigned dA0 = d[qs][0][0], dB0 = d[qs][0][1];
        unsigned dA1 = d[qs][1][0], dB1 = d[qs][1][1];
        int base = ((quad & 1) << 5) + col;
        unsigned a0  = __shfl(dA0, base),      a1  = __shfl(dA1, base);
        unsigned b0  = __shfl(dB0, base),      b1  = __shfl(dB1, base);
        unsigned a0h = __shfl(dA0, base + 16), a1h = __shfl(dA1, base + 16);
        unsigned b0h = __shfl(dB0, base + 16), b1h = __shfl(dB1, base + 16);
        bool hi = quad >= 2;
        uint4 pu = make_uint4(hi ? a1 : a0, hi ? b1 : b0,
                              hi ? a1h : a0h, hi ? b1h : b0h);
        pbf[qs] = __builtin_bit_cast(bf16x8, pu);
      }
#pragma unroll
      for (int ht = 0; ht < 4; ++ht) {
        int pg = ht >> 1;
        bool odd = ht & 1;
        int L0 = ((quad & 1) * 2) * 16 + col, L1 = L0 + 16;
        uint4 u0 = __builtin_bit_cast(uint4, vv[pg]);
        uint4 u1 = __builtin_bit_cast(uint4, vv[2 + pg]);
        unsigned s0 = odd ? u0.z : u0.x, s1 = odd ? u0.w : u0.y;
        unsigned s2 = odd ? u1.z : u1.x, s3 = odd ? u1.w : u1.y;
        unsigned d0a = __shfl(s0, L0), d1a = __shfl(s1, L0);
        unsigned d2a = __shfl(s0, L1), d3a = __shfl(s1, L1);
        unsigned d0b = __shfl(s2, L0), d1b = __shfl(s3, L0);
        unsigned d2b = __shfl(s2, L1), d3b = __shfl(s3, L1);
        bool t1 = quad >= 2;
        uint4 vu = make_uint4(t1 ? d0b : d0a, t1 ? d1b : d1a,
                              t1 ? d2b : d2a, t1 ? d3b : d3a);
        bf16x8 vf8 = __builtin_bit_cast(bf16x8, vu);
#pragma unroll
        for (int qs = 0; qs < 2; ++qs)
          o[qs][ht] = MFMA_BF16(vf8, pbf[qs], o[qs][ht]);
      }
#endif
    }

    // ---- 4-way split-K combine (pure fp32 add; no-max softmax) ----
    __syncthreads();
    float* comb = (float*)lds;  // overlays K staging
    if (wave > 0) {
      float* p = comb + ((wave - 1) * 64 + lane) * 36;
#pragma unroll
      for (int qs = 0; qs < 2; ++qs)
#pragma unroll
        for (int ht = 0; ht < 4; ++ht)
          *(f32x4*)(p + (qs * 4 + ht) * 4) = o[qs][ht];
      p[32] = osum[0];
      p[33] = osum[1];
    }
    __syncthreads();
    if (wave == 0) {
#pragma unroll
      for (int w = 1; w < 4; ++w) {
        const float* p = comb + ((w - 1) * 64 + lane) * 36;
#pragma unroll
        for (int qs = 0; qs < 2; ++qs)
#pragma unroll
          for (int ht = 0; ht < 4; ++ht)
            o[qs][ht] += *(const f32x4*)(p + (qs * 4 + ht) * 4);
        osum[0] += p[32];
        osum[1] += p[33];
      }
      // ---- epilogue: O^T C-layout -> packed float4 stores (normal stores;
      // dispatch-end flush covers host visibility) ----
#pragma unroll
      for (int qs = 0; qs < 2; ++qs) {
        float inv = 1.0f / osum[qs];
#pragma unroll
        for (int ht = 0; ht < 4; ++ht) {
          f32x4 val = o[qs][ht];
#pragma unroll
          for (int rr = 0; rr < 4; ++rr) val[rr] *= inv;
          *(f32x4*)(out + (qbase + qs * 16 + col) * 64 + ht * 16 + quad * 4) = val;
        }
      }
    }
  }
}

// ---------------------------------------------------------------------------
extern "C" void kernel_launch(void* const* d_in, const int* in_sizes, int n_in,
                              void* d_out, int out_size, void* d_ws, size_t ws_size,
                              hipStream_t stream) {
  const float* x  = (const float*)d_in[0];
  const float* Wk = (const float*)d_in[1];
  const float* Wq = (const float*)d_in[2];
  const float* Wv = (const float*)d_in[3];
  float* out = (float*)d_out;

  char* ws = (char*)d_ws;
  // ws layout: wtf (294912 B) | qb 2MB | kb 2MB | vfb 2MB | ... | bar @ 8MB
  // bar: 2 barriers x 8 counters x 128 B stride (zeroed below).
  short* wtf = (short*)(ws);
  short* qb  = (short*)(ws + (512 << 10));
  short* kb  = (short*)(ws + (512 << 10) + (2 << 20));
  short* vfb = (short*)(ws + (512 << 10) + (4 << 20));
  unsigned* bar = (unsigned*)(ws + (8 << 20));

  hipMemsetAsync(bar, 0, 4096, stream);  // zero barrier counters (capture-safe)
  fused_kernel<<<512, 256, 0, stream>>>(x, Wk, Wq, Wv, wtf, qb, kb, vfb, bar,
                                        out);
}

// Round 9
// 130.756 us; speedup vs baseline: 1.0147x; 1.0147x over previous
//
#include <hip/hip_runtime.h>

// B=8, T=2048, C=768, HS=64. fp32 in/out; bf16 MFMA internally.
// R17 = R16 + three stall fixes (all perf-only, bit-identical numerics):
//  (1) phase-B counted-vmcnt barrier (T3/T4): s_waitcnt vmcnt(1) lgkmcnt(0) +
//      raw s_barrier -- the x HBM prefetch (newest op) survives the barrier
//      instead of being force-drained ~400cyc early every k-step.
//  (2) 64-stripe barrier arrive (8 RMW/line, was 64) + s_sleep(8) poll.
//  (3) phase-C V prefetch-one-ahead (issue_v(v+4) after PV frees vv).

typedef short bf16x8 __attribute__((ext_vector_type(8)));  // 8 bf16 = 4 VGPR
typedef short bf16x4 __attribute__((ext_vector_type(4)));  // 4 bf16 = 2 VGPR
typedef float f32x4  __attribute__((ext_vector_type(4)));
typedef unsigned u32x2 __attribute__((ext_vector_type(2)));
typedef unsigned u32x4 __attribute__((ext_vector_type(4)));

#define MFMA_BF16(a, b, c) __builtin_amdgcn_mfma_f32_16x16x32_bf16((a), (b), (c), 0, 0, 0)

#if __has_builtin(__builtin_amdgcn_mfma_f32_16x16x16bf16_1k)
#define HAVE_MFMA16 1
#define MFMA16(a, b, c) __builtin_amdgcn_mfma_f32_16x16x16bf16_1k((a), (b), (c), 0, 0, 0)
#else
#define HAVE_MFMA16 0
#endif

// scale = C^-0.5 * log2(e), folded into Wq at prep time
#define SCALE_LOG2E 0.05206626f

__device__ __forceinline__ unsigned rbf(float f) {  // RNE bf16 in high 16 bits
  unsigned u = __builtin_bit_cast(unsigned, f);
  return u + 0x7fffu + ((u >> 16) & 1u);
}
__device__ __forceinline__ short f2bf(float f) { return (short)(rbf(f) >> 16); }
__device__ __forceinline__ unsigned pkbf(float a, float b) {  // [lo=a, hi=b]
  return (rbf(a) >> 16) | (rbf(b) & 0xFFFF0000u);
}
__device__ __forceinline__ float bsum(unsigned dw) {  // sum of 2 packed bf16
  float lo = __builtin_bit_cast(float, dw << 16);
  float hi = __builtin_bit_cast(float, dw & 0xFFFF0000u);
  return lo + hi;
}

__device__ __forceinline__ void load_lds16(const void* g, void* l) {
  __builtin_amdgcn_global_load_lds(
      (const __attribute__((address_space(1))) void*)g,
      (__attribute__((address_space(3))) void*)l, 16, 0, 0);
}

// System-scope write-through store (gfx950 spellings: sc0 sc1). Data reaches
// the MALL coherence point; no dirty L2 lines -> fence-free grid barrier.
__device__ __forceinline__ void st16_sys(void* p, u32x4 v) {
  asm volatile("global_store_dwordx4 %0, %1, off sc0 sc1" ::"v"(p), "v"(v)
               : "memory");
}

// Fence-free grid barrier, 64-stripe arrive (8 same-line RMWs per stripe
// instead of 64). Prereq: cross-phase data stored write-through. Drain own
// stores -> block barrier -> striped arrive -> load-only poll (s_sleep(8)
// caps poll traffic) -> compiler barrier. Timeout failsafe degrades to a
// visible wrong answer, never a hang.
__device__ __forceinline__ void gbar(unsigned* ctr, unsigned target) {
  asm volatile("s_waitcnt vmcnt(0)" ::: "memory");
  __syncthreads();
  if (threadIdx.x == 0) {
    atomicAdd(&ctr[(blockIdx.x & 63) * 32], 1u);
    long long t0 = (long long)__builtin_amdgcn_s_memtime();
    for (;;) {
      unsigned s = 0;
#pragma unroll
      for (int i = 0; i < 64; ++i)
        s += __hip_atomic_load(&ctr[i * 32], __ATOMIC_RELAXED,
                               __HIP_MEMORY_SCOPE_AGENT);
      if (s >= target) break;
      __builtin_amdgcn_s_sleep(8);
      if ((long long)__builtin_amdgcn_s_memtime() - t0 > (1LL << 28)) break;
    }
    asm volatile("" ::: "memory");  // keep later loads below the poll
  }
  __syncthreads();
}

// ---------------------------------------------------------------------------
// Fused kernel. 512 blocks x 256 threads, plain launch.
// LDS union (29696 B = 14848 shorts):
//   proj: xa[2][32][40] = shorts [0,2560) | wb[2][6144] = shorts [2560,14848)
//   proj epilogue: qk[32][128] = shorts [0,4096)  (xa/wb dead)
//   attn: ksw 4 waves x 2304 shorts = [0,9216) ; combine overlay 6912 floats
// Co-residency: __launch_bounds__(256,2) + 29.7 KB LDS -> 2 blocks/CU x 256
// CU = 512 = grid, compile-enforced.
// ---------------------------------------------------------------------------
__global__ __launch_bounds__(256, 2) void fused_kernel(
    const float* __restrict__ x, const float* __restrict__ Wk,
    const float* __restrict__ Wq, const float* __restrict__ Wv,
    short* __restrict__ wtf, short* __restrict__ qb, short* __restrict__ kb,
    short* __restrict__ vfb, unsigned* __restrict__ bar,
    float* __restrict__ out) {
  __shared__ __attribute__((aligned(16))) short lds[14848];

  const int tid  = threadIdx.x;
  const int wave = tid >> 6;
  const int lane = tid & 63;
  const int quad = lane >> 4;
  const int col  = lane & 15;

  // ============== phase A: prep wtf (B-fragment-order weights) =============
  // wtf[ks 0..23][nt 0..11][lane 0..63][8 bf16]; nt 0-3 Wq (pre-scaled),
  // 4-7 Wk, 8-11 Wv.
  {
    int gid = blockIdx.x * 256 + tid;
    if (gid < 24 * 12 * 64) {
      int ks   = gid / 768;
      int rem  = gid - ks * 768;
      int nt   = rem >> 6;
      int pl   = rem & 63;
      int pq = pl >> 4, pc = pl & 15;
      const float* W = (nt < 4) ? Wq : (nt < 8) ? Wk : Wv;
      float s = (nt < 4) ? SCALE_LOG2E : 1.0f;
      int h  = (nt & 3) * 16 + pc;
      int k0 = ks * 32 + pq * 8;
      bf16x8 v;
#pragma unroll
      for (int j = 0; j < 8; ++j) v[j] = f2bf(W[(k0 + j) * 64 + h] * s);
      st16_sys(wtf + (size_t)gid * 8, __builtin_bit_cast(u32x4, v));
    }
  }
  gbar(bar, 512);

  // ============== phase B: projections (R6 compute, counted-vmcnt sync) ====
  {
    short (*xa)[32][40] = (short(*)[32][40]) & lds[0];      // 2x32x40
    short (*wb)[6144]   = (short(*)[6144]) & lds[2560];     // 2x6144

    const int msub = wave >> 1;
    const int nh   = wave & 1;
    const int m0   = blockIdx.x * 32;

    const int srow = tid >> 3, sc4 = tid & 7;
    const float* xsrc = x + (size_t)(m0 + srow) * 768 + sc4 * 4;

    auto dma_wt = [&](int ks, int buf) {
      const short* wsrc = wtf + (size_t)ks * 6144;
#pragma unroll
      for (int i = 0; i < 3; ++i) {
        int seg = wave * 3 + i;
        load_lds16(wsrc + seg * 512 + lane * 8, &wb[buf][seg * 512]);
      }
    };
    auto write_xa = [&](int buf, const float4& xv) {
      unsigned lo = pkbf(xv.x, xv.y);
      unsigned hi = pkbf(xv.z, xv.w);
      *(uint2*)&xa[buf][srow][sc4 * 4] = make_uint2(lo, hi);
    };

    f32x4 acc[6];
#pragma unroll
    for (int i = 0; i < 6; ++i) acc[i] = (f32x4){0.f, 0.f, 0.f, 0.f};

    float4 xv = *(const float4*)xsrc;
    dma_wt(0, 0);
    write_xa(0, xv);
    xv = *(const float4*)(xsrc + 32);

    for (int ks = 0; ks < 24; ++ks) {
      const int cur = ks & 1;
      // Counted-vmcnt barrier (T3/T4): per-wave issue order is 3 DMAs (for
      // buf[cur], issued last iter) then the xv HBM prefetch -> vmcnt(1)
      // drains exactly the DMAs and lets the prefetch fly across the
      // barrier. lgkmcnt(0) publishes my xa write. Race audit: readers of
      // the buffer a DMA targets drained their ds_reads (lgkm) before the
      // PREVIOUS barrier -- write-after-read safe.
      asm volatile("s_waitcnt vmcnt(1) lgkmcnt(0)" ::: "memory");
      __builtin_amdgcn_s_barrier();

      if (ks + 1 < 24) {
        dma_wt(ks + 1, cur ^ 1);
        write_xa(cur ^ 1, xv);  // compiler waits the (oldest) xv load only
        if (ks + 2 < 24) xv = *(const float4*)(xsrc + (ks + 2) * 32);
      }

      bf16x8 af = *(const bf16x8*)&xa[cur][msub * 16 + col][quad * 8];
#pragma unroll
      for (int i = 0; i < 6; ++i) {
        bf16x8 bfr = *(const bf16x8*)&wb[cur][((nh * 6 + i) * 64 + lane) * 8];
        acc[i] = MFMA_BF16(af, bfr, acc[i]);
      }
    }

    // ---- epilogue (R16). acc C/D layout: col = lane&15, row = quad*4+rr.
    // Stage q/k through LDS tile qk[32 tok][128] (cols 0-63 q-h, 64-127 k-h),
    // then 2 coalesced 16B write-through stores per thread. V already wide.
    const int b = m0 >> 11;
    const int v = (m0 & 2047) >> 5;  // 32-key visit within batch

    __syncthreads();     // full drain; all waves past their last xa/wb reads
    short* qk = lds;     // overlays xa/wb
#pragma unroll
    for (int i = 0; i < 6; ++i) {
      int nt = nh * 6 + i;
      if (nt < 8) {  // q: nt 0-3 -> cols (nt&3)*16+col; k: nt 4-7 -> +64
        int cb = ((nt < 4) ? 0 : 64) + (nt & 3) * 16 + col;
        int r0 = msub * 16 + quad * 4;
#pragma unroll
        for (int r = 0; r < 4; ++r) qk[(r0 + r) * 128 + cb] = f2bf(acc[i][r]);
      }
    }
    if (nh == 1) {
      // V (acc[2..5]): pack straight into MFMA16 A-frag order.
#pragma unroll
      for (int pg = 0; pg < 2; ++pg) {
        unsigned w0 = pkbf(acc[2 + 2 * pg][0], acc[2 + 2 * pg][1]);
        unsigned w1 = pkbf(acc[2 + 2 * pg][2], acc[2 + 2 * pg][3]);
        unsigned w2 = pkbf(acc[3 + 2 * pg][0], acc[3 + 2 * pg][1]);
        unsigned w3 = pkbf(acc[3 + 2 * pg][2], acc[3 + 2 * pg][3]);
        u32x4 pu = {w0, w1, w2, w3};
        st16_sys(vfb + ((size_t)((b * 64 + v) * 4 + msub * 2 + pg)) * 512 + lane * 8,
                 pu);
      }
    }
    __syncthreads();
    {
      const int row = tid >> 3, sub = tid & 7;  // 32 rows x 8 col-groups
      short* dst = ((sub < 4) ? qb : kb) + (size_t)(m0 + row) * 64 + (sub & 3) * 16;
      const short* src = &qk[row * 128 + sub * 16];
      st16_sys(dst, *(const u32x4*)(src));
      st16_sys(dst + 8, *(const u32x4*)(src + 8));
    }
  }
  gbar(bar + 64 * 32, 512);

  // ============== phase C: flash attention (R8 4-way split) ================
  {
    short* ksw = &lds[wave * 2304];  // wave-private K tile [32 key][72]

    const int bx = blockIdx.x;
    const int b  = bx & 7;
    // Persistent placement pairs bx with bx+256 on one CU (round-robin
    // dispatch). Map qt so each pair is (qt, 63-qt): constant work per CU.
    const int qt = (bx < 256) ? (63 - (bx >> 3)) : ((bx - 256) >> 3);
    const size_t qbase = (size_t)b * 2048 + qt * 32;

    // Q B-frags (pre-scaled): qf[qs][c] -> Q[q=col][h=c*32+quad*8+j]
    bf16x8 qf[2][2];
#pragma unroll
    for (int qs = 0; qs < 2; ++qs)
#pragma unroll
      for (int c = 0; c < 2; ++c)
        qf[qs][c] = *(const bf16x8*)(qb + (qbase + qs * 16 + col) * 64 + c * 32 + quad * 8);

    f32x4 o[2][4];  // O^T accumulators: [qs][ht], row=h_local, col=q
#pragma unroll
    for (int qs = 0; qs < 2; ++qs)
#pragma unroll
      for (int ht = 0; ht < 4; ++ht) o[qs][ht] = (f32x4){0.f, 0.f, 0.f, 0.f};
    float osum[2] = {0.f, 0.f};

    const int nv = qt + 1;  // 32-key visits; wave w takes w, w+4, ...
    const int mycount = (nv > wave) ? ((nv - wave + 3) >> 2) : 0;

    const short* kB = kb + (size_t)b * 2048 * 64;
    const short* vB = vfb + (size_t)b * 64 * 4 * 512;

    bf16x8 kreg[4], vv[4];
    auto issue_k = [&](int v) {  // contiguous 4 KB
      const short* ksrc = kB + (size_t)v * 32 * 64;
#pragma unroll
      for (int it = 0; it < 4; ++it)
        kreg[it] = *(const bf16x8*)(ksrc + lane * 8 + it * 512);
    };
    auto issue_v = [&](int v) {  // frag-order, 1 KB contiguous per load
      const short* vp = vB + (size_t)v * 4 * 512;
#pragma unroll
      for (int g = 0; g < 4; ++g)
        vv[g] = *(const bf16x8*)(vp + g * 512 + lane * 8);
    };
    if (mycount > 0) { issue_k(wave); issue_v(wave); }  // V prefetched too

    for (int i = 0; i < mycount; ++i) {
      const int v = wave + i * 4;

      // ---- commit prefetched K to private LDS (consumes kreg) ----
#pragma unroll
      for (int it = 0; it < 4; ++it) {
        int e = lane * 8 + it * 512;
        *(bf16x8*)&ksw[(e >> 6) * 72 + (e & 63)] = kreg[it];  // [key][h]
      }
      if (i + 1 < mycount) issue_k(v + 4);  // K prefetch for next visit

      // ---- S^T = K Q^T : A=K[key][h] from LDS, B=Q (regs) ----
      f32x4 st[2][2];  // [qs][t: 16-key tile]
#pragma unroll
      for (int qs = 0; qs < 2; ++qs)
#pragma unroll
        for (int t = 0; t < 2; ++t) st[qs][t] = (f32x4){0.f, 0.f, 0.f, 0.f};
#pragma unroll
      for (int t = 0; t < 2; ++t) {
        const bf16x8 a0 = *(const bf16x8*)&ksw[(t * 16 + col) * 72 + quad * 8];
        const bf16x8 a1 = *(const bf16x8*)&ksw[(t * 16 + col) * 72 + 32 + quad * 8];
#pragma unroll
        for (int qs = 0; qs < 2; ++qs) {
          st[qs][t] = MFMA_BF16(a0, qf[qs][0], st[qs][t]);
          st[qs][t] = MFMA_BF16(a1, qf[qs][1], st[qs][t]);
        }
      }

      // ---- p = exp2(s); causal mask on diagonal visit ----
      const bool diag = (v == qt);  // wave-uniform
      unsigned d[2][2][2];          // packed bf16 P: [qs][t][pair]
#pragma unroll
      for (int qs = 0; qs < 2; ++qs) {
        float part = 0.f;
#pragma unroll
        for (int t = 0; t < 2; ++t) {
          float pr[4];
#pragma unroll
          for (int rr = 0; rr < 4; ++rr) {
            float sv = st[qs][t][rr];
            if (diag && (t * 16 + quad * 4 + rr) > (qs * 16 + col)) sv = -1e30f;
            pr[rr] = __builtin_amdgcn_exp2f(sv);
          }
          d[qs][t][0] = pkbf(pr[0], pr[1]);
          d[qs][t][1] = pkbf(pr[2], pr[3]);
          part += bsum(d[qs][t][0]) + bsum(d[qs][t][1]);
        }
        part += __shfl_xor(part, 16);
        part += __shfl_xor(part, 32);
        osum[qs] += part;
      }

#if HAVE_MFMA16
      // ---- O^T += V^T P^T : V frags straight from vv regs, P from d regs --
#pragma unroll
      for (int t = 0; t < 2; ++t)
#pragma unroll
        for (int pg = 0; pg < 2; ++pg) {
          uint4 u = __builtin_bit_cast(uint4, vv[t * 2 + pg]);
          u32x2 l2 = {u.x, u.y}, h2 = {u.z, u.w};
          bf16x4 vlo = __builtin_bit_cast(bf16x4, l2);  // ht = 2*pg
          bf16x4 vhi = __builtin_bit_cast(bf16x4, h2);  // ht = 2*pg+1
#pragma unroll
          for (int qs = 0; qs < 2; ++qs) {
            u32x2 pd = {d[qs][t][0], d[qs][t][1]};
            bf16x4 pb = __builtin_bit_cast(bf16x4, pd);
            o[qs][2 * pg]     = MFMA16(vlo, pb, o[qs][2 * pg]);
            o[qs][2 * pg + 1] = MFMA16(vhi, pb, o[qs][2 * pg + 1]);
          }
        }
#else
      // ---- fallback: shfl-transpose P (K=32) + shfl-gather V bf16x8 ----
      bf16x8 pbf[2];
#pragma unroll
      for (int qs = 0; qs < 2; ++qs) {
        unsigned dA0 = d[qs][0][0], dB0 = d[qs][0][1];
        unsigned dA1 = d[qs][1][0], dB1 = d[qs][1][1];
        int base = ((quad & 1) << 5) + col;
        unsigned a0  = __shfl(dA0, base),      a1  = __shfl(dA1, base);
        unsigned b0  = __shfl(dB0, base),      b1  = __shfl(dB1, base);
        unsigned a0h = __shfl(dA0, base + 16), a1h = __shfl(dA1, base + 16);
        unsigned b0h = __shfl(dB0, base + 16), b1h = __shfl(dB1, base + 16);
        bool hi = quad >= 2;
        uint4 pu = make_uint4(hi ? a1 : a0, hi ? b1 : b0,
                              hi ? a1h : a0h, hi ? b1h : b0h);
        pbf[qs] = __builtin_bit_cast(bf16x8, pu);
      }
#pragma unroll
      for (int ht = 0; ht < 4; ++ht) {
        int pg = ht >> 1;
        bool odd = ht & 1;
        int L0 = ((quad & 1) * 2) * 16 + col, L1 = L0 + 16;
        uint4 u0 = __builtin_bit_cast(uint4, vv[pg]);
        uint4 u1 = __builtin_bit_cast(uint4, vv[2 + pg]);
        unsigned s0 = odd ? u0.z : u0.x, s1 = odd ? u0.w : u0.y;
        unsigned s2 = odd ? u1.z : u1.x, s3 = odd ? u1.w : u1.y;
        unsigned d0a = __shfl(s0, L0), d1a = __shfl(s1, L0);
        unsigned d2a = __shfl(s0, L1), d3a = __shfl(s1, L1);
        unsigned d0b = __shfl(s2, L0), d1b = __shfl(s3, L0);
        unsigned d2b = __shfl(s2, L1), d3b = __shfl(s3, L1);
        bool t1 = quad >= 2;
        uint4 vu = make_uint4(t1 ? d0b : d0a, t1 ? d1b : d1a,
                              t1 ? d2b : d2a, t1 ? d3b : d3a);
        bf16x8 vf8 = __builtin_bit_cast(bf16x8, vu);
#pragma unroll
        for (int qs = 0; qs < 2; ++qs)
          o[qs][ht] = MFMA_BF16(vf8, pbf[qs], o[qs][ht]);
      }
#endif
      if (i + 1 < mycount) issue_v(v + 4);  // vv free after PV: ~1 visit lead
    }

    // ---- 4-way split-K combine (pure fp32 add; no-max softmax) ----
    __syncthreads();
    float* comb = (float*)lds;  // overlays K staging
    if (wave > 0) {
      float* p = comb + ((wave - 1) * 64 + lane) * 36;
#pragma unroll
      for (int qs = 0; qs < 2; ++qs)
#pragma unroll
        for (int ht = 0; ht < 4; ++ht)
          *(f32x4*)(p + (qs * 4 + ht) * 4) = o[qs][ht];
      p[32] = osum[0];
      p[33] = osum[1];
    }
    __syncthreads();
    if (wave == 0) {
#pragma unroll
      for (int w = 1; w < 4; ++w) {
        const float* p = comb + ((w - 1) * 64 + lane) * 36;
#pragma unroll
        for (int qs = 0; qs < 2; ++qs)
#pragma unroll
          for (int ht = 0; ht < 4; ++ht)
            o[qs][ht] += *(const f32x4*)(p + (qs * 4 + ht) * 4);
        osum[0] += p[32];
        osum[1] += p[33];
      }
      // ---- epilogue: O^T C-layout -> packed float4 stores (normal stores;
      // dispatch-end flush covers host visibility) ----
#pragma unroll
      for (int qs = 0; qs < 2; ++qs) {
        float inv = 1.0f / osum[qs];
#pragma unroll
        for (int ht = 0; ht < 4; ++ht) {
          f32x4 val = o[qs][ht];
#pragma unroll
          for (int rr = 0; rr < 4; ++rr) val[rr] *= inv;
          *(f32x4*)(out + (qbase + qs * 16 + col) * 64 + ht * 16 + quad * 4) = val;
        }
      }
    }
  }
}

// ---------------------------------------------------------------------------
extern "C" void kernel_launch(void* const* d_in, const int* in_sizes, int n_in,
                              void* d_out, int out_size, void* d_ws, size_t ws_size,
                              hipStream_t stream) {
  const float* x  = (const float*)d_in[0];
  const float* Wk = (const float*)d_in[1];
  const float* Wq = (const float*)d_in[2];
  const float* Wv = (const float*)d_in[3];
  float* out = (float*)d_out;

  char* ws = (char*)d_ws;
  // ws layout: wtf (294912 B) | qb 2MB | kb 2MB | vfb 2MB | ... | bar @ 8MB
  // bar: 2 barriers x 64 counters x 128 B stride = 16384 B (zeroed below).
  short* wtf = (short*)(ws);
  short* qb  = (short*)(ws + (512 << 10));
  short* kb  = (short*)(ws + (512 << 10) + (2 << 20));
  short* vfb = (short*)(ws + (512 << 10) + (4 << 20));
  unsigned* bar = (unsigned*)(ws + (8 << 20));

  hipMemsetAsync(bar, 0, 16384, stream);  // zero barrier counters (capture-safe)
  fused_kernel<<<512, 256, 0, stream>>>(x, Wk, Wq, Wv, wtf, qb, kb, vfb, bar,
                                        out);
}

// Round 10
// 127.974 us; speedup vs baseline: 1.0368x; 1.0217x over previous
//
#include <hip/hip_runtime.h>

// B=8, T=2048, C=768, HS=64. fp32 in/out; bf16 MFMA internally.
// R18 = R17 + two barrier-level fixes (numerics untouched):
//  (a) last-iter vmcnt(0) in phase B -- R17's vmcnt(1) left one DMA in
//      flight into the buffer being read at ks=23 (latent race).
//  (b) two-level release barrier: block 0 aggregates the 64 arrive-stripes;
//      all others poll ONE release word with s_sleep(16). R17's 64-load
//      agent-scope poll x512 blocks flooded the MALL (~150 loads/ns during
//      barrier windows), throttling the arrives/write-throughs themselves.

typedef short bf16x8 __attribute__((ext_vector_type(8)));  // 8 bf16 = 4 VGPR
typedef short bf16x4 __attribute__((ext_vector_type(4)));  // 4 bf16 = 2 VGPR
typedef float f32x4  __attribute__((ext_vector_type(4)));
typedef unsigned u32x2 __attribute__((ext_vector_type(2)));
typedef unsigned u32x4 __attribute__((ext_vector_type(4)));

#define MFMA_BF16(a, b, c) __builtin_amdgcn_mfma_f32_16x16x32_bf16((a), (b), (c), 0, 0, 0)

#if __has_builtin(__builtin_amdgcn_mfma_f32_16x16x16bf16_1k)
#define HAVE_MFMA16 1
#define MFMA16(a, b, c) __builtin_amdgcn_mfma_f32_16x16x16bf16_1k((a), (b), (c), 0, 0, 0)
#else
#define HAVE_MFMA16 0
#endif

// scale = C^-0.5 * log2(e), folded into Wq at prep time
#define SCALE_LOG2E 0.05206626f

__device__ __forceinline__ unsigned rbf(float f) {  // RNE bf16 in high 16 bits
  unsigned u = __builtin_bit_cast(unsigned, f);
  return u + 0x7fffu + ((u >> 16) & 1u);
}
__device__ __forceinline__ short f2bf(float f) { return (short)(rbf(f) >> 16); }
__device__ __forceinline__ unsigned pkbf(float a, float b) {  // [lo=a, hi=b]
  return (rbf(a) >> 16) | (rbf(b) & 0xFFFF0000u);
}
__device__ __forceinline__ float bsum(unsigned dw) {  // sum of 2 packed bf16
  float lo = __builtin_bit_cast(float, dw << 16);
  float hi = __builtin_bit_cast(float, dw & 0xFFFF0000u);
  return lo + hi;
}

__device__ __forceinline__ void load_lds16(const void* g, void* l) {
  __builtin_amdgcn_global_load_lds(
      (const __attribute__((address_space(1))) void*)g,
      (__attribute__((address_space(3))) void*)l, 16, 0, 0);
}

// System-scope write-through store (gfx950 spellings: sc0 sc1). Data reaches
// the MALL coherence point; no dirty L2 lines -> fence-free grid barrier.
__device__ __forceinline__ void st16_sys(void* p, u32x4 v) {
  asm volatile("global_store_dwordx4 %0, %1, off sc0 sc1" ::"v"(p), "v"(v)
               : "memory");
}

// Fence-free two-level grid barrier. Prereq: cross-phase data stored
// write-through. Drain own stores -> block barrier -> striped device-scope
// arrive -> block 0 aggregates stripes and publishes `rel`; all others poll
// the single release word (1 agent load per ~0.4us instead of 64 per 0.2us
// -- the R17 poll flooded the MALL). Timeout failsafes in both roles keep
// failure mode = visible wrong answer, never a hang.
__device__ __forceinline__ void gbar(unsigned* ctr, unsigned* rel,
                                     unsigned target) {
  asm volatile("s_waitcnt vmcnt(0)" ::: "memory");
  __syncthreads();
  if (threadIdx.x == 0) {
    atomicAdd(&ctr[(blockIdx.x & 63) * 32], 1u);
    long long t0 = (long long)__builtin_amdgcn_s_memtime();
    if (blockIdx.x == 0) {  // aggregator: one block flooding is harmless
      for (;;) {
        unsigned s = 0;
#pragma unroll
        for (int i = 0; i < 64; ++i)
          s += __hip_atomic_load(&ctr[i * 32], __ATOMIC_RELAXED,
                                 __HIP_MEMORY_SCOPE_AGENT);
        if (s >= target) break;
        __builtin_amdgcn_s_sleep(2);
        if ((long long)__builtin_amdgcn_s_memtime() - t0 > (1LL << 28)) break;
      }
      __hip_atomic_store(rel, 1u, __ATOMIC_RELAXED, __HIP_MEMORY_SCOPE_AGENT);
    } else {  // everyone else: poll ONE word, slowly
      while (__hip_atomic_load(rel, __ATOMIC_RELAXED,
                               __HIP_MEMORY_SCOPE_AGENT) == 0) {
        __builtin_amdgcn_s_sleep(16);
        if ((long long)__builtin_amdgcn_s_memtime() - t0 > (1LL << 28)) break;
      }
    }
    asm volatile("" ::: "memory");  // keep later loads below the poll
  }
  __syncthreads();
}

// ---------------------------------------------------------------------------
// Fused kernel. 512 blocks x 256 threads, plain launch.
// LDS union (29696 B = 14848 shorts):
//   proj: xa[2][32][40] = shorts [0,2560) | wb[2][6144] = shorts [2560,14848)
//   proj epilogue: qk[32][128] = shorts [0,4096)  (xa/wb dead)
//   attn: ksw 4 waves x 2304 shorts = [0,9216) ; combine overlay 6912 floats
// Co-residency: __launch_bounds__(256,2) + 29.7 KB LDS -> 2 blocks/CU x 256
// CU = 512 = grid, compile-enforced.
// ---------------------------------------------------------------------------
__global__ __launch_bounds__(256, 2) void fused_kernel(
    const float* __restrict__ x, const float* __restrict__ Wk,
    const float* __restrict__ Wq, const float* __restrict__ Wv,
    short* __restrict__ wtf, short* __restrict__ qb, short* __restrict__ kb,
    short* __restrict__ vfb, unsigned* __restrict__ bar,
    float* __restrict__ out) {
  __shared__ __attribute__((aligned(16))) short lds[14848];

  const int tid  = threadIdx.x;
  const int wave = tid >> 6;
  const int lane = tid & 63;
  const int quad = lane >> 4;
  const int col  = lane & 15;

  // ============== phase A: prep wtf (B-fragment-order weights) =============
  // wtf[ks 0..23][nt 0..11][lane 0..63][8 bf16]; nt 0-3 Wq (pre-scaled),
  // 4-7 Wk, 8-11 Wv.
  {
    int gid = blockIdx.x * 256 + tid;
    if (gid < 24 * 12 * 64) {
      int ks   = gid / 768;
      int rem  = gid - ks * 768;
      int nt   = rem >> 6;
      int pl   = rem & 63;
      int pq = pl >> 4, pc = pl & 15;
      const float* W = (nt < 4) ? Wq : (nt < 8) ? Wk : Wv;
      float s = (nt < 4) ? SCALE_LOG2E : 1.0f;
      int h  = (nt & 3) * 16 + pc;
      int k0 = ks * 32 + pq * 8;
      bf16x8 v;
#pragma unroll
      for (int j = 0; j < 8; ++j) v[j] = f2bf(W[(k0 + j) * 64 + h] * s);
      st16_sys(wtf + (size_t)gid * 8, __builtin_bit_cast(u32x4, v));
    }
  }
  gbar(bar, bar + 128 * 32, 512);

  // ============== phase B: projections (R6 compute, counted-vmcnt sync) ====
  {
    short (*xa)[32][40] = (short(*)[32][40]) & lds[0];      // 2x32x40
    short (*wb)[6144]   = (short(*)[6144]) & lds[2560];     // 2x6144

    const int msub = wave >> 1;
    const int nh   = wave & 1;
    const int m0   = blockIdx.x * 32;

    const int srow = tid >> 3, sc4 = tid & 7;
    const float* xsrc = x + (size_t)(m0 + srow) * 768 + sc4 * 4;

    auto dma_wt = [&](int ks, int buf) {
      const short* wsrc = wtf + (size_t)ks * 6144;
#pragma unroll
      for (int i = 0; i < 3; ++i) {
        int seg = wave * 3 + i;
        load_lds16(wsrc + seg * 512 + lane * 8, &wb[buf][seg * 512]);
      }
    };
    auto write_xa = [&](int buf, const float4& xv) {
      unsigned lo = pkbf(xv.x, xv.y);
      unsigned hi = pkbf(xv.z, xv.w);
      *(uint2*)&xa[buf][srow][sc4 * 4] = make_uint2(lo, hi);
    };

    f32x4 acc[6];
#pragma unroll
    for (int i = 0; i < 6; ++i) acc[i] = (f32x4){0.f, 0.f, 0.f, 0.f};

    float4 xv = *(const float4*)xsrc;
    dma_wt(0, 0);
    write_xa(0, xv);
    xv = *(const float4*)(xsrc + 32);

    for (int ks = 0; ks < 24; ++ks) {
      const int cur = ks & 1;
      // Counted-vmcnt barrier (T3/T4): per-wave issue order is 3 DMAs (for
      // buf[cur], issued last iter) then the xv HBM prefetch -> vmcnt(1)
      // drains exactly the DMAs and lets the prefetch fly across the
      // barrier. Last iteration has NO newer op after the DMAs -> must
      // drain fully (R17 left 1 DMA in flight: latent race, now fixed).
      if (ks < 23) {
        asm volatile("s_waitcnt vmcnt(1) lgkmcnt(0)" ::: "memory");
      } else {
        asm volatile("s_waitcnt vmcnt(0) lgkmcnt(0)" ::: "memory");
      }
      __builtin_amdgcn_s_barrier();

      if (ks + 1 < 24) {
        dma_wt(ks + 1, cur ^ 1);
        write_xa(cur ^ 1, xv);  // compiler waits the (oldest) xv load only
        if (ks + 2 < 24) xv = *(const float4*)(xsrc + (ks + 2) * 32);
      }

      bf16x8 af = *(const bf16x8*)&xa[cur][msub * 16 + col][quad * 8];
#pragma unroll
      for (int i = 0; i < 6; ++i) {
        bf16x8 bfr = *(const bf16x8*)&wb[cur][((nh * 6 + i) * 64 + lane) * 8];
        acc[i] = MFMA_BF16(af, bfr, acc[i]);
      }
    }

    // ---- epilogue (R16). acc C/D layout: col = lane&15, row = quad*4+rr.
    // Stage q/k through LDS tile qk[32 tok][128] (cols 0-63 q-h, 64-127 k-h),
    // then 2 coalesced 16B write-through stores per thread. V already wide.
    const int b = m0 >> 11;
    const int v = (m0 & 2047) >> 5;  // 32-key visit within batch

    __syncthreads();     // all waves past their last xa/wb reads
    short* qk = lds;     // overlays xa/wb
#pragma unroll
    for (int i = 0; i < 6; ++i) {
      int nt = nh * 6 + i;
      if (nt < 8) {  // q: nt 0-3 -> cols (nt&3)*16+col; k: nt 4-7 -> +64
        int cb = ((nt < 4) ? 0 : 64) + (nt & 3) * 16 + col;
        int r0 = msub * 16 + quad * 4;
#pragma unroll
        for (int r = 0; r < 4; ++r) qk[(r0 + r) * 128 + cb] = f2bf(acc[i][r]);
      }
    }
    if (nh == 1) {
      // V (acc[2..5]): pack straight into MFMA16 A-frag order.
#pragma unroll
      for (int pg = 0; pg < 2; ++pg) {
        unsigned w0 = pkbf(acc[2 + 2 * pg][0], acc[2 + 2 * pg][1]);
        unsigned w1 = pkbf(acc[2 + 2 * pg][2], acc[2 + 2 * pg][3]);
        unsigned w2 = pkbf(acc[3 + 2 * pg][0], acc[3 + 2 * pg][1]);
        unsigned w3 = pkbf(acc[3 + 2 * pg][2], acc[3 + 2 * pg][3]);
        u32x4 pu = {w0, w1, w2, w3};
        st16_sys(vfb + ((size_t)((b * 64 + v) * 4 + msub * 2 + pg)) * 512 + lane * 8,
                 pu);
      }
    }
    __syncthreads();
    {
      const int row = tid >> 3, sub = tid & 7;  // 32 rows x 8 col-groups
      short* dst = ((sub < 4) ? qb : kb) + (size_t)(m0 + row) * 64 + (sub & 3) * 16;
      const short* src = &qk[row * 128 + sub * 16];
      st16_sys(dst, *(const u32x4*)(src));
      st16_sys(dst + 8, *(const u32x4*)(src + 8));
    }
  }
  gbar(bar + 64 * 32, bar + 128 * 32 + 32, 512);

  // ============== phase C: flash attention (R8 4-way split) ================
  {
    short* ksw = &lds[wave * 2304];  // wave-private K tile [32 key][72]

    const int bx = blockIdx.x;
    const int b  = bx & 7;
    // Persistent placement pairs bx with bx+256 on one CU (round-robin
    // dispatch). Map qt so each pair is (qt, 63-qt): constant work per CU.
    const int qt = (bx < 256) ? (63 - (bx >> 3)) : ((bx - 256) >> 3);
    const size_t qbase = (size_t)b * 2048 + qt * 32;

    // Q B-frags (pre-scaled): qf[qs][c] -> Q[q=col][h=c*32+quad*8+j]
    bf16x8 qf[2][2];
#pragma unroll
    for (int qs = 0; qs < 2; ++qs)
#pragma unroll
      for (int c = 0; c < 2; ++c)
        qf[qs][c] = *(const bf16x8*)(qb + (qbase + qs * 16 + col) * 64 + c * 32 + quad * 8);

    f32x4 o[2][4];  // O^T accumulators: [qs][ht], row=h_local, col=q
#pragma unroll
    for (int qs = 0; qs < 2; ++qs)
#pragma unroll
      for (int ht = 0; ht < 4; ++ht) o[qs][ht] = (f32x4){0.f, 0.f, 0.f, 0.f};
    float osum[2] = {0.f, 0.f};

    const int nv = qt + 1;  // 32-key visits; wave w takes w, w+4, ...
    const int mycount = (nv > wave) ? ((nv - wave + 3) >> 2) : 0;

    const short* kB = kb + (size_t)b * 2048 * 64;
    const short* vB = vfb + (size_t)b * 64 * 4 * 512;

    bf16x8 kreg[4], vv[4];
    auto issue_k = [&](int v) {  // contiguous 4 KB
      const short* ksrc = kB + (size_t)v * 32 * 64;
#pragma unroll
      for (int it = 0; it < 4; ++it)
        kreg[it] = *(const bf16x8*)(ksrc + lane * 8 + it * 512);
    };
    auto issue_v = [&](int v) {  // frag-order, 1 KB contiguous per load
      const short* vp = vB + (size_t)v * 4 * 512;
#pragma unroll
      for (int g = 0; g < 4; ++g)
        vv[g] = *(const bf16x8*)(vp + g * 512 + lane * 8);
    };
    if (mycount > 0) { issue_k(wave); issue_v(wave); }  // V prefetched too

    for (int i = 0; i < mycount; ++i) {
      const int v = wave + i * 4;

      // ---- commit prefetched K to private LDS (consumes kreg) ----
#pragma unroll
      for (int it = 0; it < 4; ++it) {
        int e = lane * 8 + it * 512;
        *(bf16x8*)&ksw[(e >> 6) * 72 + (e & 63)] = kreg[it];  // [key][h]
      }
      if (i + 1 < mycount) issue_k(v + 4);  // K prefetch for next visit

      // ---- S^T = K Q^T : A=K[key][h] from LDS, B=Q (regs) ----
      f32x4 st[2][2];  // [qs][t: 16-key tile]
#pragma unroll
      for (int qs = 0; qs < 2; ++qs)
#pragma unroll
        for (int t = 0; t < 2; ++t) st[qs][t] = (f32x4){0.f, 0.f, 0.f, 0.f};
#pragma unroll
      for (int t = 0; t < 2; ++t) {
        const bf16x8 a0 = *(const bf16x8*)&ksw[(t * 16 + col) * 72 + quad * 8];
        const bf16x8 a1 = *(const bf16x8*)&ksw[(t * 16 + col) * 72 + 32 + quad * 8];
#pragma unroll
        for (int qs = 0; qs < 2; ++qs) {
          st[qs][t] = MFMA_BF16(a0, qf[qs][0], st[qs][t]);
          st[qs][t] = MFMA_BF16(a1, qf[qs][1], st[qs][t]);
        }
      }

      // ---- p = exp2(s); causal mask on diagonal visit ----
      const bool diag = (v == qt);  // wave-uniform
      unsigned d[2][2][2];          // packed bf16 P: [qs][t][pair]
#pragma unroll
      for (int qs = 0; qs < 2; ++qs) {
        float part = 0.f;
#pragma unroll
        for (int t = 0; t < 2; ++t) {
          float pr[4];
#pragma unroll
          for (int rr = 0; rr < 4; ++rr) {
            float sv = st[qs][t][rr];
            if (diag && (t * 16 + quad * 4 + rr) > (qs * 16 + col)) sv = -1e30f;
            pr[rr] = __builtin_amdgcn_exp2f(sv);
          }
          d[qs][t][0] = pkbf(pr[0], pr[1]);
          d[qs][t][1] = pkbf(pr[2], pr[3]);
          part += bsum(d[qs][t][0]) + bsum(d[qs][t][1]);
        }
        part += __shfl_xor(part, 16);
        part += __shfl_xor(part, 32);
        osum[qs] += part;
      }

#if HAVE_MFMA16
      // ---- O^T += V^T P^T : V frags straight from vv regs, P from d regs --
#pragma unroll
      for (int t = 0; t < 2; ++t)
#pragma unroll
        for (int pg = 0; pg < 2; ++pg) {
          uint4 u = __builtin_bit_cast(uint4, vv[t * 2 + pg]);
          u32x2 l2 = {u.x, u.y}, h2 = {u.z, u.w};
          bf16x4 vlo = __builtin_bit_cast(bf16x4, l2);  // ht = 2*pg
          bf16x4 vhi = __builtin_bit_cast(bf16x4, h2);  // ht = 2*pg+1
#pragma unroll
          for (int qs = 0; qs < 2; ++qs) {
            u32x2 pd = {d[qs][t][0], d[qs][t][1]};
            bf16x4 pb = __builtin_bit_cast(bf16x4, pd);
            o[qs][2 * pg]     = MFMA16(vlo, pb, o[qs][2 * pg]);
            o[qs][2 * pg + 1] = MFMA16(vhi, pb, o[qs][2 * pg + 1]);
          }
        }
#else
      // ---- fallback: shfl-transpose P (K=32) + shfl-gather V bf16x8 ----
      bf16x8 pbf[2];
#pragma unroll
      for (int qs = 0; qs < 2; ++qs) {
        unsigned dA0 = d[qs][0][0], dB0 = d[qs][0][1];
        unsigned dA1 = d[qs][1][0], dB1 = d[qs][1][1];
        int base = ((quad & 1) << 5) + col;
        unsigned a0  = __shfl(dA0, base),      a1  = __shfl(dA1, base);
        unsigned b0  = __shfl(dB0, base),      b1  = __shfl(dB1, base);
        unsigned a0h = __shfl(dA0, base + 16), a1h = __shfl(dA1, base + 16);
        unsigned b0h = __shfl(dB0, base + 16), b1h = __shfl(dB1, base + 16);
        bool hi = quad >= 2;
        uint4 pu = make_uint4(hi ? a1 : a0, hi ? b1 : b0,
                              hi ? a1h : a0h, hi ? b1h : b0h);
        pbf[qs] = __builtin_bit_cast(bf16x8, pu);
      }
#pragma unroll
      for (int ht = 0; ht < 4; ++ht) {
        int pg = ht >> 1;
        bool odd = ht & 1;
        int L0 = ((quad & 1) * 2) * 16 + col, L1 = L0 + 16;
        uint4 u0 = __builtin_bit_cast(uint4, vv[pg]);
        uint4 u1 = __builtin_bit_cast(uint4, vv[2 + pg]);
        unsigned s0 = odd ? u0.z : u0.x, s1 = odd ? u0.w : u0.y;
        unsigned s2 = odd ? u1.z : u1.x, s3 = odd ? u1.w : u1.y;
        unsigned d0a = __shfl(s0, L0), d1a = __shfl(s1, L0);
        unsigned d2a = __shfl(s0, L1), d3a = __shfl(s1, L1);
        unsigned d0b = __shfl(s2, L0), d1b = __shfl(s3, L0);
        unsigned d2b = __shfl(s2, L1), d3b = __shfl(s3, L1);
        bool t1 = quad >= 2;
        uint4 vu = make_uint4(t1 ? d0b : d0a, t1 ? d1b : d1a,
                              t1 ? d2b : d2a, t1 ? d3b : d3a);
        bf16x8 vf8 = __builtin_bit_cast(bf16x8, vu);
#pragma unroll
        for (int qs = 0; qs < 2; ++qs)
          o[qs][ht] = MFMA_BF16(vf8, pbf[qs], o[qs][ht]);
      }
#endif
      if (i + 1 < mycount) issue_v(v + 4);  // vv free after PV: ~1 visit lead
    }

    // ---- 4-way split-K combine (pure fp32 add; no-max softmax) ----
    __syncthreads();
    float* comb = (float*)lds;  // overlays K staging
    if (wave > 0) {
      float* p = comb + ((wave - 1) * 64 + lane) * 36;
#pragma unroll
      for (int qs = 0; qs < 2; ++qs)
#pragma unroll
        for (int ht = 0; ht < 4; ++ht)
          *(f32x4*)(p + (qs * 4 + ht) * 4) = o[qs][ht];
      p[32] = osum[0];
      p[33] = osum[1];
    }
    __syncthreads();
    if (wave == 0) {
#pragma unroll
      for (int w = 1; w < 4; ++w) {
        const float* p = comb + ((w - 1) * 64 + lane) * 36;
#pragma unroll
        for (int qs = 0; qs < 2; ++qs)
#pragma unroll
          for (int ht = 0; ht < 4; ++ht)
            o[qs][ht] += *(const f32x4*)(p + (qs * 4 + ht) * 4);
        osum[0] += p[32];
        osum[1] += p[33];
      }
      // ---- epilogue: O^T C-layout -> packed float4 stores (normal stores;
      // dispatch-end flush covers host visibility) ----
#pragma unroll
      for (int qs = 0; qs < 2; ++qs) {
        float inv = 1.0f / osum[qs];
#pragma unroll
        for (int ht = 0; ht < 4; ++ht) {
          f32x4 val = o[qs][ht];
#pragma unroll
          for (int rr = 0; rr < 4; ++rr) val[rr] *= inv;
          *(f32x4*)(out + (qbase + qs * 16 + col) * 64 + ht * 16 + quad * 4) = val;
        }
      }
    }
  }
}

// ---------------------------------------------------------------------------
extern "C" void kernel_launch(void* const* d_in, const int* in_sizes, int n_in,
                              void* d_out, int out_size, void* d_ws, size_t ws_size,
                              hipStream_t stream) {
  const float* x  = (const float*)d_in[0];
  const float* Wk = (const float*)d_in[1];
  const float* Wq = (const float*)d_in[2];
  const float* Wv = (const float*)d_in[3];
  float* out = (float*)d_out;

  char* ws = (char*)d_ws;
  // ws layout: wtf (294912 B) | qb 2MB | kb 2MB | vfb 2MB | ... | bar @ 8MB
  // bar: 2 barriers x 64 stripes x 128 B + 2 release words (zeroed below).
  short* wtf = (short*)(ws);
  short* qb  = (short*)(ws + (512 << 10));
  short* kb  = (short*)(ws + (512 << 10) + (2 << 20));
  short* vfb = (short*)(ws + (512 << 10) + (4 << 20));
  unsigned* bar = (unsigned*)(ws + (8 << 20));

  hipMemsetAsync(bar, 0, 20480, stream);  // zero stripes + release words
  fused_kernel<<<512, 256, 0, stream>>>(x, Wk, Wq, Wv, wtf, qb, kb, vfb, bar,
                                        out);
}

// Round 12
// 118.411 us; speedup vs baseline: 1.1205x; 1.0808x over previous
//
#include <hip/hip_runtime.h>

// B=8, T=2048, C=768, HS=64. fp32 in/out; bf16 MFMA internally.
// R20 = R19 resubmission (container died infra-side last round; R19's only
// delta vs the thrice-run R18 is phase B's inner loop -- no hang mechanism;
// index algebra re-audited). Phase B: stage x ONCE in LDS (bf16 [32][776],
// 16B-aligned rows), then a ZERO-BARRIER MFMA loop streaming wtf B-frags
// straight from global to registers (wtf is already in frag order: 16B/lane
// contiguous, L2-resident), double-buffered 1 k-step ahead. MFMA inputs
// bit-identical to R18. Phases A/C, epilogue, gbar: R18-verbatim.

typedef short bf16x8 __attribute__((ext_vector_type(8)));  // 8 bf16 = 4 VGPR
typedef short bf16x4 __attribute__((ext_vector_type(4)));  // 4 bf16 = 2 VGPR
typedef float f32x4  __attribute__((ext_vector_type(4)));
typedef unsigned u32x2 __attribute__((ext_vector_type(2)));
typedef unsigned u32x4 __attribute__((ext_vector_type(4)));

#define MFMA_BF16(a, b, c) __builtin_amdgcn_mfma_f32_16x16x32_bf16((a), (b), (c), 0, 0, 0)

#if __has_builtin(__builtin_amdgcn_mfma_f32_16x16x16bf16_1k)
#define HAVE_MFMA16 1
#define MFMA16(a, b, c) __builtin_amdgcn_mfma_f32_16x16x16bf16_1k((a), (b), (c), 0, 0, 0)
#else
#define HAVE_MFMA16 0
#endif

// scale = C^-0.5 * log2(e), folded into Wq at prep time
#define SCALE_LOG2E 0.05206626f

__device__ __forceinline__ unsigned rbf(float f) {  // RNE bf16 in high 16 bits
  unsigned u = __builtin_bit_cast(unsigned, f);
  return u + 0x7fffu + ((u >> 16) & 1u);
}
__device__ __forceinline__ short f2bf(float f) { return (short)(rbf(f) >> 16); }
__device__ __forceinline__ unsigned pkbf(float a, float b) {  // [lo=a, hi=b]
  return (rbf(a) >> 16) | (rbf(b) & 0xFFFF0000u);
}
__device__ __forceinline__ float bsum(unsigned dw) {  // sum of 2 packed bf16
  float lo = __builtin_bit_cast(float, dw << 16);
  float hi = __builtin_bit_cast(float, dw & 0xFFFF0000u);
  return lo + hi;
}

// System-scope write-through store (gfx950 spellings: sc0 sc1). Data reaches
// the MALL coherence point; no dirty L2 lines -> fence-free grid barrier.
__device__ __forceinline__ void st16_sys(void* p, u32x4 v) {
  asm volatile("global_store_dwordx4 %0, %1, off sc0 sc1" ::"v"(p), "v"(v)
               : "memory");
}

// Fence-free two-level grid barrier (R18). Drain own stores -> block barrier
// -> striped device-scope arrive -> block 0 aggregates and publishes `rel`;
// others poll the single release word. Timeout failsafes keep failure mode =
// visible wrong answer, never a hang.
__device__ __forceinline__ void gbar(unsigned* ctr, unsigned* rel,
                                     unsigned target) {
  asm volatile("s_waitcnt vmcnt(0)" ::: "memory");
  __syncthreads();
  if (threadIdx.x == 0) {
    atomicAdd(&ctr[(blockIdx.x & 63) * 32], 1u);
    long long t0 = (long long)__builtin_amdgcn_s_memtime();
    if (blockIdx.x == 0) {
      for (;;) {
        unsigned s = 0;
#pragma unroll
        for (int i = 0; i < 64; ++i)
          s += __hip_atomic_load(&ctr[i * 32], __ATOMIC_RELAXED,
                                 __HIP_MEMORY_SCOPE_AGENT);
        if (s >= target) break;
        __builtin_amdgcn_s_sleep(2);
        if ((long long)__builtin_amdgcn_s_memtime() - t0 > (1LL << 28)) break;
      }
      __hip_atomic_store(rel, 1u, __ATOMIC_RELAXED, __HIP_MEMORY_SCOPE_AGENT);
    } else {
      while (__hip_atomic_load(rel, __ATOMIC_RELAXED,
                               __HIP_MEMORY_SCOPE_AGENT) == 0) {
        __builtin_amdgcn_s_sleep(16);
        if ((long long)__builtin_amdgcn_s_memtime() - t0 > (1LL << 28)) break;
      }
    }
    asm volatile("" ::: "memory");  // keep later loads below the poll
  }
  __syncthreads();
}

// ---------------------------------------------------------------------------
// Fused kernel. 512 blocks x 256 threads, plain launch.
// LDS union (49664 B = 24832 shorts):
//   B: xs[32][776] bf16 x-tile = 24832 shorts (staged once, then read-only)
//   B epilogue: qk[32][128] = shorts [0,4096)  (xs dead)
//   C: ksw 4 waves x 2304 shorts = [0,9216) ; combine overlay 6912 floats
// Co-residency: __launch_bounds__(256,2) + 49.7 KB LDS (2x = 99 KB < 160 KB)
// -> 2 blocks/CU x 256 CU = 512 = grid.
// ---------------------------------------------------------------------------
__global__ __launch_bounds__(256, 2) void fused_kernel(
    const float* __restrict__ x, const float* __restrict__ Wk,
    const float* __restrict__ Wq, const float* __restrict__ Wv,
    short* __restrict__ wtf, short* __restrict__ qb, short* __restrict__ kb,
    short* __restrict__ vfb, unsigned* __restrict__ bar,
    float* __restrict__ out) {
  __shared__ __attribute__((aligned(16))) short lds[24832];

  const int tid  = threadIdx.x;
  const int wave = tid >> 6;
  const int lane = tid & 63;
  const int quad = lane >> 4;
  const int col  = lane & 15;

  // ============== phase A: prep wtf (B-fragment-order weights) =============
  // wtf[ks 0..23][nt 0..11][lane 0..63][8 bf16]; nt 0-3 Wq (pre-scaled),
  // 4-7 Wk, 8-11 Wv.
  {
    int gid = blockIdx.x * 256 + tid;
    if (gid < 24 * 12 * 64) {
      int ks   = gid / 768;
      int rem  = gid - ks * 768;
      int nt   = rem >> 6;
      int pl   = rem & 63;
      int pq = pl >> 4, pc = pl & 15;
      const float* W = (nt < 4) ? Wq : (nt < 8) ? Wk : Wv;
      float s = (nt < 4) ? SCALE_LOG2E : 1.0f;
      int h  = (nt & 3) * 16 + pc;
      int k0 = ks * 32 + pq * 8;
      bf16x8 v;
#pragma unroll
      for (int j = 0; j < 8; ++j) v[j] = f2bf(W[(k0 + j) * 64 + h] * s);
      st16_sys(wtf + (size_t)gid * 8, __builtin_bit_cast(u32x4, v));
    }
  }
  gbar(bar, bar + 128 * 32, 512);

  // ============== phase B: projections (x-in-LDS, zero-barrier loop) =======
  {
    short* xs = lds;  // [32][776] bf16, row stride 776 (rows 16B-aligned)

    const int msub = wave >> 1;
    const int nh   = wave & 1;
    const int m0   = blockIdx.x * 32;

    // ---- stage x tile once: 32 rows x 768 fp32 -> bf16. float4 f-index
    // row-major over [32][192]; consecutive tids = consecutive 16B. ----
#pragma unroll 4
    for (int it = 0; it < 24; ++it) {
      int f   = tid + it * 256;        // [0, 6144)
      int row = f / 192, c4 = f - row * 192;
      float4 xv = *(const float4*)(x + (size_t)(m0 + row) * 768 + c4 * 4);
      unsigned lo = pkbf(xv.x, xv.y);
      unsigned hi = pkbf(xv.z, xv.w);
      *(uint2*)&xs[row * 776 + c4 * 4] = make_uint2(lo, hi);
    }
    __syncthreads();

    // ---- MFMA loop: B-frags straight from wtf (frag order: 16B/lane
    // contiguous, L2-resident), double-buffered one k-step ahead. ----
    f32x4 acc[6];
#pragma unroll
    for (int i = 0; i < 6; ++i) acc[i] = (f32x4){0.f, 0.f, 0.f, 0.f};

    auto ldw = [&](int ks, bf16x8* dst) {
      const short* p = wtf + (size_t)ks * 6144 + ((nh * 6) * 64 + lane) * 8;
#pragma unroll
      for (int i = 0; i < 6; ++i) dst[i] = *(const bf16x8*)(p + i * 512);
    };
    auto lda = [&](int ks) {
      return *(const bf16x8*)&xs[(msub * 16 + col) * 776 + ks * 32 + quad * 8];
    };

    bf16x8 bc[6], bn[6];
    ldw(0, bc);
    bf16x8 af = lda(0);
    for (int ks = 0; ks < 24; ++ks) {
      if (ks + 1 < 24) ldw(ks + 1, bn);
      bf16x8 afn = (ks + 1 < 24) ? lda(ks + 1) : af;
#pragma unroll
      for (int i = 0; i < 6; ++i) acc[i] = MFMA_BF16(af, bc[i], acc[i]);
#pragma unroll
      for (int i = 0; i < 6; ++i) bc[i] = bn[i];
      af = afn;
    }

    // ---- epilogue (R16/R18 verbatim). acc C/D: col=lane&15, row=quad*4+rr.
    // Stage q/k through LDS tile qk[32][128] (overlays xs, dead), then 2
    // coalesced 16B write-through stores per thread. V direct (frag order).
    const int b = m0 >> 11;
    const int v = (m0 & 2047) >> 5;  // 32-key visit within batch

    __syncthreads();     // all waves past their last xs reads
    short* qk = lds;     // overlays xs
#pragma unroll
    for (int i = 0; i < 6; ++i) {
      int nt = nh * 6 + i;
      if (nt < 8) {  // q: nt 0-3 -> cols (nt&3)*16+col; k: nt 4-7 -> +64
        int cb = ((nt < 4) ? 0 : 64) + (nt & 3) * 16 + col;
        int r0 = msub * 16 + quad * 4;
#pragma unroll
        for (int r = 0; r < 4; ++r) qk[(r0 + r) * 128 + cb] = f2bf(acc[i][r]);
      }
    }
    if (nh == 1) {
      // V (acc[2..5]): pack straight into MFMA16 A-frag order.
#pragma unroll
      for (int pg = 0; pg < 2; ++pg) {
        unsigned w0 = pkbf(acc[2 + 2 * pg][0], acc[2 + 2 * pg][1]);
        unsigned w1 = pkbf(acc[2 + 2 * pg][2], acc[2 + 2 * pg][3]);
        unsigned w2 = pkbf(acc[3 + 2 * pg][0], acc[3 + 2 * pg][1]);
        unsigned w3 = pkbf(acc[3 + 2 * pg][2], acc[3 + 2 * pg][3]);
        u32x4 pu = {w0, w1, w2, w3};
        st16_sys(vfb + ((size_t)((b * 64 + v) * 4 + msub * 2 + pg)) * 512 + lane * 8,
                 pu);
      }
    }
    __syncthreads();
    {
      const int row = tid >> 3, sub = tid & 7;  // 32 rows x 8 col-groups
      short* dst = ((sub < 4) ? qb : kb) + (size_t)(m0 + row) * 64 + (sub & 3) * 16;
      const short* src = &qk[row * 128 + sub * 16];
      st16_sys(dst, *(const u32x4*)(src));
      st16_sys(dst + 8, *(const u32x4*)(src + 8));
    }
  }
  gbar(bar + 64 * 32, bar + 128 * 32 + 32, 512);

  // ============== phase C: flash attention (R18 verbatim) ==================
  {
    short* ksw = &lds[wave * 2304];  // wave-private K tile [32 key][72]

    const int bx = blockIdx.x;
    const int b  = bx & 7;
    // Persistent placement pairs bx with bx+256 on one CU; map qt so each
    // pair is (qt, 63-qt): constant work per CU (perf-only heuristic).
    const int qt = (bx < 256) ? (63 - (bx >> 3)) : ((bx - 256) >> 3);
    const size_t qbase = (size_t)b * 2048 + qt * 32;

    // Q B-frags (pre-scaled): qf[qs][c] -> Q[q=col][h=c*32+quad*8+j]
    bf16x8 qf[2][2];
#pragma unroll
    for (int qs = 0; qs < 2; ++qs)
#pragma unroll
      for (int c = 0; c < 2; ++c)
        qf[qs][c] = *(const bf16x8*)(qb + (qbase + qs * 16 + col) * 64 + c * 32 + quad * 8);

    f32x4 o[2][4];  // O^T accumulators: [qs][ht], row=h_local, col=q
#pragma unroll
    for (int qs = 0; qs < 2; ++qs)
#pragma unroll
      for (int ht = 0; ht < 4; ++ht) o[qs][ht] = (f32x4){0.f, 0.f, 0.f, 0.f};
    float osum[2] = {0.f, 0.f};

    const int nv = qt + 1;  // 32-key visits; wave w takes w, w+4, ...
    const int mycount = (nv > wave) ? ((nv - wave + 3) >> 2) : 0;

    const short* kB = kb + (size_t)b * 2048 * 64;
    const short* vB = vfb + (size_t)b * 64 * 4 * 512;

    bf16x8 kreg[4], vv[4];
    auto issue_k = [&](int v) {  // contiguous 4 KB
      const short* ksrc = kB + (size_t)v * 32 * 64;
#pragma unroll
      for (int it = 0; it < 4; ++it)
        kreg[it] = *(const bf16x8*)(ksrc + lane * 8 + it * 512);
    };
    auto issue_v = [&](int v) {  // frag-order, 1 KB contiguous per load
      const short* vp = vB + (size_t)v * 4 * 512;
#pragma unroll
      for (int g = 0; g < 4; ++g)
        vv[g] = *(const bf16x8*)(vp + g * 512 + lane * 8);
    };
    if (mycount > 0) { issue_k(wave); issue_v(wave); }

    for (int i = 0; i < mycount; ++i) {
      const int v = wave + i * 4;

      // ---- commit prefetched K to private LDS (consumes kreg) ----
#pragma unroll
      for (int it = 0; it < 4; ++it) {
        int e = lane * 8 + it * 512;
        *(bf16x8*)&ksw[(e >> 6) * 72 + (e & 63)] = kreg[it];  // [key][h]
      }
      if (i + 1 < mycount) issue_k(v + 4);  // K prefetch for next visit

      // ---- S^T = K Q^T : A=K[key][h] from LDS, B=Q (regs) ----
      f32x4 st[2][2];  // [qs][t: 16-key tile]
#pragma unroll
      for (int qs = 0; qs < 2; ++qs)
#pragma unroll
        for (int t = 0; t < 2; ++t) st[qs][t] = (f32x4){0.f, 0.f, 0.f, 0.f};
#pragma unroll
      for (int t = 0; t < 2; ++t) {
        const bf16x8 a0 = *(const bf16x8*)&ksw[(t * 16 + col) * 72 + quad * 8];
        const bf16x8 a1 = *(const bf16x8*)&ksw[(t * 16 + col) * 72 + 32 + quad * 8];
#pragma unroll
        for (int qs = 0; qs < 2; ++qs) {
          st[qs][t] = MFMA_BF16(a0, qf[qs][0], st[qs][t]);
          st[qs][t] = MFMA_BF16(a1, qf[qs][1], st[qs][t]);
        }
      }

      // ---- p = exp2(s); causal mask on diagonal visit ----
      const bool diag = (v == qt);  // wave-uniform
      unsigned d[2][2][2];          // packed bf16 P: [qs][t][pair]
#pragma unroll
      for (int qs = 0; qs < 2; ++qs) {
        float part = 0.f;
#pragma unroll
        for (int t = 0; t < 2; ++t) {
          float pr[4];
#pragma unroll
          for (int rr = 0; rr < 4; ++rr) {
            float sv = st[qs][t][rr];
            if (diag && (t * 16 + quad * 4 + rr) > (qs * 16 + col)) sv = -1e30f;
            pr[rr] = __builtin_amdgcn_exp2f(sv);
          }
          d[qs][t][0] = pkbf(pr[0], pr[1]);
          d[qs][t][1] = pkbf(pr[2], pr[3]);
          part += bsum(d[qs][t][0]) + bsum(d[qs][t][1]);
        }
        part += __shfl_xor(part, 16);
        part += __shfl_xor(part, 32);
        osum[qs] += part;
      }

#if HAVE_MFMA16
      // ---- O^T += V^T P^T : V frags straight from vv regs, P from d regs --
#pragma unroll
      for (int t = 0; t < 2; ++t)
#pragma unroll
        for (int pg = 0; pg < 2; ++pg) {
          uint4 u = __builtin_bit_cast(uint4, vv[t * 2 + pg]);
          u32x2 l2 = {u.x, u.y}, h2 = {u.z, u.w};
          bf16x4 vlo = __builtin_bit_cast(bf16x4, l2);  // ht = 2*pg
          bf16x4 vhi = __builtin_bit_cast(bf16x4, h2);  // ht = 2*pg+1
#pragma unroll
          for (int qs = 0; qs < 2; ++qs) {
            u32x2 pd = {d[qs][t][0], d[qs][t][1]};
            bf16x4 pb = __builtin_bit_cast(bf16x4, pd);
            o[qs][2 * pg]     = MFMA16(vlo, pb, o[qs][2 * pg]);
            o[qs][2 * pg + 1] = MFMA16(vhi, pb, o[qs][2 * pg + 1]);
          }
        }
#else
      // ---- fallback: shfl-transpose P (K=32) + shfl-gather V bf16x8 ----
      bf16x8 pbf[2];
#pragma unroll
      for (int qs = 0; qs < 2; ++qs) {
        unsigned dA0 = d[qs][0][0], dB0 = d[qs][0][1];
        unsigned dA1 = d[qs][1][0], dB1 = d[qs][1][1];
        int base = ((quad & 1) << 5) + col;
        unsigned a0  = __shfl(dA0, base),      a1  = __shfl(dA1, base);
        unsigned b0  = __shfl(dB0, base),      b1  = __shfl(dB1, base);
        unsigned a0h = __shfl(dA0, base + 16), a1h = __shfl(dA1, base + 16);
        unsigned b0h = __shfl(dB0, base + 16), b1h = __shfl(dB1, base + 16);
        bool hi = quad >= 2;
        uint4 pu = make_uint4(hi ? a1 : a0, hi ? b1 : b0,
                              hi ? a1h : a0h, hi ? b1h : b0h);
        pbf[qs] = __builtin_bit_cast(bf16x8, pu);
      }
#pragma unroll
      for (int ht = 0; ht < 4; ++ht) {
        int pg = ht >> 1;
        bool odd = ht & 1;
        int L0 = ((quad & 1) * 2) * 16 + col, L1 = L0 + 16;
        uint4 u0 = __builtin_bit_cast(uint4, vv[pg]);
        uint4 u1 = __builtin_bit_cast(uint4, vv[2 + pg]);
        unsigned s0 = odd ? u0.z : u0.x, s1 = odd ? u0.w : u0.y;
        unsigned s2 = odd ? u1.z : u1.x, s3 = odd ? u1.w : u1.y;
        unsigned d0a = __shfl(s0, L0), d1a = __shfl(s1, L0);
        unsigned d2a = __shfl(s0, L1), d3a = __shfl(s1, L1);
        unsigned d0b = __shfl(s2, L0), d1b = __shfl(s3, L0);
        unsigned d2b = __shfl(s2, L1), d3b = __shfl(s3, L1);
        bool t1 = quad >= 2;
        uint4 vu = make_uint4(t1 ? d0b : d0a, t1 ? d1b : d1a,
                              t1 ? d2b : d2a, t1 ? d3b : d3a);
        bf16x8 vf8 = __builtin_bit_cast(bf16x8, vu);
#pragma unroll
        for (int qs = 0; qs < 2; ++qs)
          o[qs][ht] = MFMA_BF16(vf8, pbf[qs], o[qs][ht]);
      }
#endif
      if (i + 1 < mycount) issue_v(v + 4);  // vv free after PV: 1 visit lead
    }

    // ---- 4-way split-K combine (pure fp32 add; no-max softmax) ----
    __syncthreads();
    float* comb = (float*)lds;  // overlays K staging
    if (wave > 0) {
      float* p = comb + ((wave - 1) * 64 + lane) * 36;
#pragma unroll
      for (int qs = 0; qs < 2; ++qs)
#pragma unroll
        for (int ht = 0; ht < 4; ++ht)
          *(f32x4*)(p + (qs * 4 + ht) * 4) = o[qs][ht];
      p[32] = osum[0];
      p[33] = osum[1];
    }
    __syncthreads();
    if (wave == 0) {
#pragma unroll
      for (int w = 1; w < 4; ++w) {
        const float* p = comb + ((w - 1) * 64 + lane) * 36;
#pragma unroll
        for (int qs = 0; qs < 2; ++qs)
#pragma unroll
          for (int ht = 0; ht < 4; ++ht)
            o[qs][ht] += *(const f32x4*)(p + (qs * 4 + ht) * 4);
        osum[0] += p[32];
        osum[1] += p[33];
      }
      // ---- epilogue: O^T C-layout -> packed float4 stores ----
#pragma unroll
      for (int qs = 0; qs < 2; ++qs) {
        float inv = 1.0f / osum[qs];
#pragma unroll
        for (int ht = 0; ht < 4; ++ht) {
          f32x4 val = o[qs][ht];
#pragma unroll
          for (int rr = 0; rr < 4; ++rr) val[rr] *= inv;
          *(f32x4*)(out + (qbase + qs * 16 + col) * 64 + ht * 16 + quad * 4) = val;
        }
      }
    }
  }
}

// ---------------------------------------------------------------------------
extern "C" void kernel_launch(void* const* d_in, const int* in_sizes, int n_in,
                              void* d_out, int out_size, void* d_ws, size_t ws_size,
                              hipStream_t stream) {
  const float* x  = (const float*)d_in[0];
  const float* Wk = (const float*)d_in[1];
  const float* Wq = (const float*)d_in[2];
  const float* Wv = (const float*)d_in[3];
  float* out = (float*)d_out;

  char* ws = (char*)d_ws;
  // ws layout: wtf (294912 B) | qb 2MB | kb 2MB | vfb 2MB | ... | bar @ 8MB
  // bar: 2 barriers x 64 stripes x 128 B + 2 release words (zeroed below).
  short* wtf = (short*)(ws);
  short* qb  = (short*)(ws + (512 << 10));
  short* kb  = (short*)(ws + (512 << 10) + (2 << 20));
  short* vfb = (short*)(ws + (512 << 10) + (4 << 20));
  unsigned* bar = (unsigned*)(ws + (8 << 20));

  hipMemsetAsync(bar, 0, 20480, stream);  // zero stripes + release words
  fused_kernel<<<512, 256, 0, stream>>>(x, Wk, Wq, Wv, wtf, qb, kb, vfb, bar,
                                        out);
}